// Round 14
// baseline (16.287 us; speedup 1.0000x reference)
//
#include <hip/hip_runtime.h>
#include <math.h>

#define BB 32
#define LL 128
#define DD 256
#define HH 1024   // 4*D

__device__ __forceinline__ float waveReduceSum(float v) {
#pragma unroll
    for (int m = 32; m >= 1; m >>= 1) v += __shfl_xor(v, m, 64);
    return v;
}

// Single dispatch, 256 blocks x 1024 threads; block (b = blk&31, q8 = blk>>5).
// All 8 blocks of a batch land on the same XCD (blk%8==b%8 under round-robin),
// so duplicate a1/a2 reads merge in that XCD's L2.
// Register-resident rows: wave g (0..15), lane d4 (0..63) holds float4 column
// d4 of a1 rows 8g..8g+7 and a2 rows 8g..8g+7 (64 VGPRs). Row-dots are 16
// interleaved butterfly reduces; pooled (phase 4) is pure register FMA.
// Factorized softmax: exp(s1_i - s2_j) = e^{s1_i} * e^{-s2_j}; masked pairs
// (|we|<1e-7, incl. all invalid with we==0) contribute exp(-1e7)=0 after
// masking; their unmasked e^{we}~=1 value is removed via count subtraction.
// denom = S1*S2 - M, M = sum of per-row masked counts over valid rows.
// rsv[i]=(E1[i]*S2-cnt_i)*dinv, csv[j]=(E2m[j]*S1-cnt'_j)*dinv fold the
// correction, so pooled = sum_i rsv[i]*A1[i,:] - csv[j]*A2[j,:] exactly.
__global__ __launch_bounds__(1024) void batch_reg_kernel(
    const float* __restrict__ a1, const int* __restrict__ len1,
    const float* __restrict__ a2, const int* __restrict__ len2,
    const float* __restrict__ fcw, const float* __restrict__ fcb,
    const float* __restrict__ ww, float* __restrict__ out)
{
    const int blk  = blockIdx.x;
    const int b    = blk & 31;     // batch
    const int q8   = blk >> 5;     // h-eighth 0..7
    const int tid  = threadIdx.x;
    const int wave = tid >> 6;     // 0..15
    const int lane = tid & 63;

    __shared__ __align__(16) float4 part4[1024];          // 16 KB
    __shared__ __align__(16) float4 wws4[DD / 4];
    __shared__ float s1[LL], s2[LL], E1[LL], E2m[LL];
    __shared__ float rsv[LL], csv[LL];
    __shared__ float redS[16], redM[16];
    __shared__ __align__(16) float4 ps4[DD / 4];

    const int l1 = len1[b];
    const int l2 = len2[b];

    if (tid < DD / 4) wws4[tid] = ((const float4*)ww)[tid];
    __syncthreads();

    const float4* __restrict__ A1v = (const float4*)(a1 + (size_t)b * LL * DD);
    const float4* __restrict__ A2v = (const float4*)(a2 + (size_t)b * LL * DD);

    // ---- phase 1: register-resident loads + 16 interleaved row-dot reduces ----
    const int r0 = wave * 8;               // first row this wave owns
    const float4 w4 = wws4[lane];

    float4 va0 = A1v[(r0 + 0) * 64 + lane];
    float4 va1 = A1v[(r0 + 1) * 64 + lane];
    float4 va2 = A1v[(r0 + 2) * 64 + lane];
    float4 va3 = A1v[(r0 + 3) * 64 + lane];
    float4 va4 = A1v[(r0 + 4) * 64 + lane];
    float4 va5 = A1v[(r0 + 5) * 64 + lane];
    float4 va6 = A1v[(r0 + 6) * 64 + lane];
    float4 va7 = A1v[(r0 + 7) * 64 + lane];
    float4 vb0 = A2v[(r0 + 0) * 64 + lane];
    float4 vb1 = A2v[(r0 + 1) * 64 + lane];
    float4 vb2 = A2v[(r0 + 2) * 64 + lane];
    float4 vb3 = A2v[(r0 + 3) * 64 + lane];
    float4 vb4 = A2v[(r0 + 4) * 64 + lane];
    float4 vb5 = A2v[(r0 + 5) * 64 + lane];
    float4 vb6 = A2v[(r0 + 6) * 64 + lane];
    float4 vb7 = A2v[(r0 + 7) * 64 + lane];

    {
        float d1[8], d2[8];
        d1[0] = va0.x * w4.x + va0.y * w4.y + va0.z * w4.z + va0.w * w4.w;
        d1[1] = va1.x * w4.x + va1.y * w4.y + va1.z * w4.z + va1.w * w4.w;
        d1[2] = va2.x * w4.x + va2.y * w4.y + va2.z * w4.z + va2.w * w4.w;
        d1[3] = va3.x * w4.x + va3.y * w4.y + va3.z * w4.z + va3.w * w4.w;
        d1[4] = va4.x * w4.x + va4.y * w4.y + va4.z * w4.z + va4.w * w4.w;
        d1[5] = va5.x * w4.x + va5.y * w4.y + va5.z * w4.z + va5.w * w4.w;
        d1[6] = va6.x * w4.x + va6.y * w4.y + va6.z * w4.z + va6.w * w4.w;
        d1[7] = va7.x * w4.x + va7.y * w4.y + va7.z * w4.z + va7.w * w4.w;
        d2[0] = vb0.x * w4.x + vb0.y * w4.y + vb0.z * w4.z + vb0.w * w4.w;
        d2[1] = vb1.x * w4.x + vb1.y * w4.y + vb1.z * w4.z + vb1.w * w4.w;
        d2[2] = vb2.x * w4.x + vb2.y * w4.y + vb2.z * w4.z + vb2.w * w4.w;
        d2[3] = vb3.x * w4.x + vb3.y * w4.y + vb3.z * w4.z + vb3.w * w4.w;
        d2[4] = vb4.x * w4.x + vb4.y * w4.y + vb4.z * w4.z + vb4.w * w4.w;
        d2[5] = vb5.x * w4.x + vb5.y * w4.y + vb5.z * w4.z + vb5.w * w4.w;
        d2[6] = vb6.x * w4.x + vb6.y * w4.y + vb6.z * w4.z + vb6.w * w4.w;
        d2[7] = vb7.x * w4.x + vb7.y * w4.y + vb7.z * w4.z + vb7.w * w4.w;
#pragma unroll
        for (int m = 32; m >= 1; m >>= 1) {
#pragma unroll
            for (int k = 0; k < 8; ++k) {
                d1[k] += __shfl_xor(d1[k], m, 64);
                d2[k] += __shfl_xor(d2[k], m, 64);
            }
        }
        if (lane == 0) {
#pragma unroll
            for (int k = 0; k < 8; ++k) {
                s1[r0 + k] = d1[k];
                s2[r0 + k] = d2[k];
            }
        }
    }
    __syncthreads();

    // ---- phase 2: E1=e^{s1}, E2m=e^{-s2}; S1,S2 over valid entries ----
    {
        float v = 0.f;
        if (tid < LL) {
            const float e = expf(s1[tid]);
            E1[tid] = e;
            if (tid < l1) v = e;
        } else if (tid < 2 * LL) {
            const int j = tid - LL;
            const float e = expf(-s2[j]);
            E2m[j] = e;
            if (j < l2) v = e;
        }
        v = waveReduceSum(v);
        if (lane == 0) redS[wave] = v;     // waves 0,1 -> S1; waves 2,3 -> S2
    }
    __syncthreads();

    // ---- phase 3a: per-row / per-col masked counts, runtime-bounded loops ----
    {
        const int rr  = tid >> 2;          // 0..255
        const int sub = tid & 3;
        int c = 0;
        if (rr < LL) {
            if (rr < l1) {
                const float si = s1[rr];
                for (int j = sub; j < l2; j += 4)
                    if (fabsf(si - s2[j]) < 1e-7f) c++;
            }
        } else {
            const int jj = rr - LL;
            if (jj < l2) {
                const float sj = s2[jj];
                for (int i = sub; i < l1; i += 4)
                    if (fabsf(s1[i] - sj) < 1e-7f) c++;
            }
        }
        c += __shfl_xor(c, 1, 64);
        c += __shfl_xor(c, 2, 64);
        if (sub == 0) {
            if (rr < LL) rsv[rr] = (float)c;       // raw row count
            else         csv[rr - LL] = (float)c;  // raw col count
        }
    }
    __syncthreads();

    // ---- phase 3b: Mtot = sum of row counts over valid rows -> dinv ----
    {
        float mc = (tid < LL && tid < l1) ? rsv[tid] : 0.f;
        mc = waveReduceSum(mc);
        if (lane == 0) redM[wave] = mc;
    }
    __syncthreads();
    const float S1 = redS[0] + redS[1];
    const float S2 = redS[2] + redS[3];
    const float Mtot = redM[0] + redM[1];      // only waves 0,1 have tid<LL
    const float dinv = 1.0f / (S1 * S2 - Mtot);

    // ---- phase 3c: finalize rsv/csv (pre-scaled by dinv) ----
    if (tid < LL)
        rsv[tid] = (tid < l1) ? (E1[tid] * S2 - rsv[tid]) * dinv : 0.f;
    else if (tid < 2 * LL) {
        const int j = tid - LL;
        csv[j] = (j < l2) ? (E2m[j] * S1 - csv[j]) * dinv : 0.f;
    }
    __syncthreads();

    // ---- phase 4: pooled partials, pure register FMA ----
    {
        float4 acc = make_float4(0.f, 0.f, 0.f, 0.f);
        float r_, c_;
        r_ = rsv[r0 + 0]; c_ = csv[r0 + 0];
        acc.x += r_ * va0.x - c_ * vb0.x; acc.y += r_ * va0.y - c_ * vb0.y;
        acc.z += r_ * va0.z - c_ * vb0.z; acc.w += r_ * va0.w - c_ * vb0.w;
        r_ = rsv[r0 + 1]; c_ = csv[r0 + 1];
        acc.x += r_ * va1.x - c_ * vb1.x; acc.y += r_ * va1.y - c_ * vb1.y;
        acc.z += r_ * va1.z - c_ * vb1.z; acc.w += r_ * va1.w - c_ * vb1.w;
        r_ = rsv[r0 + 2]; c_ = csv[r0 + 2];
        acc.x += r_ * va2.x - c_ * vb2.x; acc.y += r_ * va2.y - c_ * vb2.y;
        acc.z += r_ * va2.z - c_ * vb2.z; acc.w += r_ * va2.w - c_ * vb2.w;
        r_ = rsv[r0 + 3]; c_ = csv[r0 + 3];
        acc.x += r_ * va3.x - c_ * vb3.x; acc.y += r_ * va3.y - c_ * vb3.y;
        acc.z += r_ * va3.z - c_ * vb3.z; acc.w += r_ * va3.w - c_ * vb3.w;
        r_ = rsv[r0 + 4]; c_ = csv[r0 + 4];
        acc.x += r_ * va4.x - c_ * vb4.x; acc.y += r_ * va4.y - c_ * vb4.y;
        acc.z += r_ * va4.z - c_ * vb4.z; acc.w += r_ * va4.w - c_ * vb4.w;
        r_ = rsv[r0 + 5]; c_ = csv[r0 + 5];
        acc.x += r_ * va5.x - c_ * vb5.x; acc.y += r_ * va5.y - c_ * vb5.y;
        acc.z += r_ * va5.z - c_ * vb5.z; acc.w += r_ * va5.w - c_ * vb5.w;
        r_ = rsv[r0 + 6]; c_ = csv[r0 + 6];
        acc.x += r_ * va6.x - c_ * vb6.x; acc.y += r_ * va6.y - c_ * vb6.y;
        acc.z += r_ * va6.z - c_ * vb6.z; acc.w += r_ * va6.w - c_ * vb6.w;
        r_ = rsv[r0 + 7]; c_ = csv[r0 + 7];
        acc.x += r_ * va7.x - c_ * vb7.x; acc.y += r_ * va7.y - c_ * vb7.y;
        acc.z += r_ * va7.z - c_ * vb7.z; acc.w += r_ * va7.w - c_ * vb7.w;
        part4[tid] = acc;
    }
    __syncthreads();
    // two-step partial reduction: 256 threads x 4, then 64 x 4
    if (tid < 256) {
        float4 p = part4[tid];
        const float4 p1 = part4[256 + tid];
        const float4 p2 = part4[512 + tid];
        const float4 p3 = part4[768 + tid];
        p.x += p1.x + p2.x + p3.x;
        p.y += p1.y + p2.y + p3.y;
        p.z += p1.z + p2.z + p3.z;
        p.w += p1.w + p2.w + p3.w;
        part4[tid] = p;
    }
    __syncthreads();
    if (tid < 64) {
        float4 p = part4[tid];
        const float4 p1 = part4[64 + tid];
        const float4 p2 = part4[128 + tid];
        const float4 p3 = part4[192 + tid];
        p.x += p1.x + p2.x + p3.x;
        p.y += p1.y + p2.y + p3.y;
        p.z += p1.z + p2.z + p3.z;
        p.w += p1.w + p2.w + p3.w;
        ps4[tid] = p;
    }
    __syncthreads();

    // ---- phase 5: FC + tanh for eighth q8: 128 h rows, 64 rows/pass, 2 passes ----
    {
        const int hl  = tid >> 4;          // 0..63
        const int t16 = tid & 15;
        const float4 u0 = ps4[t16];
        const float4 u1 = ps4[16 + t16];
        const float4 u2 = ps4[32 + t16];
        const float4 u3 = ps4[48 + t16];
        float* __restrict__ outb = out + (size_t)b * HH;
#pragma unroll
        for (int pass = 0; pass < 2; ++pass) {
            const int h = q8 * 128 + pass * 64 + hl;
            const float4* __restrict__ wrow = (const float4*)(fcw + (size_t)h * DD);
            const float4 v0 = wrow[t16];
            const float4 v1 = wrow[16 + t16];
            const float4 v2 = wrow[32 + t16];
            const float4 v3 = wrow[48 + t16];
            float acc = v0.x * u0.x + v0.y * u0.y + v0.z * u0.z + v0.w * u0.w;
            acc      += v1.x * u1.x + v1.y * u1.y + v1.z * u1.z + v1.w * u1.w;
            acc      += v2.x * u2.x + v2.y * u2.y + v2.z * u2.z + v2.w * u2.w;
            acc      += v3.x * u3.x + v3.y * u3.y + v3.z * u3.z + v3.w * u3.w;
            acc += __shfl_xor(acc, 1, 64);
            acc += __shfl_xor(acc, 2, 64);
            acc += __shfl_xor(acc, 4, 64);
            acc += __shfl_xor(acc, 8, 64);
            if (t16 == 0) outb[h] = tanhf(acc + fcb[h]);
        }
    }
}

extern "C" void kernel_launch(void* const* d_in, const int* in_sizes, int n_in,
                              void* d_out, int out_size, void* d_ws, size_t ws_size,
                              hipStream_t stream) {
    const float* a1   = (const float*)d_in[0];
    const int*   len1 = (const int*)d_in[1];
    const float* a2   = (const float*)d_in[2];
    const int*   len2 = (const int*)d_in[3];
    const float* fcw  = (const float*)d_in[4];
    const float* fcb  = (const float*)d_in[5];
    const float* ww   = (const float*)d_in[6];
    float* out = (float*)d_out;

    batch_reg_kernel<<<256, 1024, 0, stream>>>(a1, len1, a2, len2, fcw, fcb, ww, out);
}

// Round 16
// 14.166 us; speedup vs baseline: 1.1497x; 1.1497x over previous
//
#include <hip/hip_runtime.h>
#include <math.h>

#define BB 32
#define LL 128
#define DD 256
#define HH 1024   // 4*D
#define A1STRIDE 65   // float4 units per cached a1 row (260 floats: +4 pad)

__device__ __forceinline__ float waveReduceSum(float v) {
#pragma unroll
    for (int m = 32; m >= 1; m >>= 1) v += __shfl_xor(v, m, 64);
    return v;
}

// Single dispatch, 256 blocks x 1024 threads; block (b = blk&31, q8 = blk>>5).
// All 8 blocks of a batch land on the same XCD (blk%8==b%8 under round-robin),
// so duplicate a1/a2 reads merge in that XCD's L2. Each block: phases 1-4 for
// batch b (a1 cached in LDS during phase 1; phase 4 reads a1 from LDS, a2 from
// L2, float4-vectorized), then eighth q8 of FC+tanh (128 KB of fcw).
// Factorized softmax: exp(s1_i - s2_j) = e^{s1_i} * e^{-s2_j}; masked pairs
// (|we|<1e-7, incl. all invalid with we==0) contribute exp(-1e7)=0 after
// masking; their unmasked e^{we}~=1 value is removed via count subtraction.
// denom = S1*S2 - M, with M = sum of per-row masked counts over valid rows.
// No global max needed: |s| small => no fp32 overflow.
// R15 hardening: raw mask-counts live in dedicated cntR/cntC arrays (no LDS
// word changes meaning across a barrier; removes the only read-then-overwrite
// aliasing pattern, suspected in the R15 post-timing divergence flake).
__global__ __launch_bounds__(1024) void batch_oct_kernel(
    const float* __restrict__ a1, const int* __restrict__ len1,
    const float* __restrict__ a2, const int* __restrict__ len2,
    const float* __restrict__ fcw, const float* __restrict__ fcb,
    const float* __restrict__ ww, float* __restrict__ out)
{
    const int blk  = blockIdx.x;
    const int b    = blk & 31;     // batch
    const int q8   = blk >> 5;     // h-eighth 0..7
    const int tid  = threadIdx.x;
    const int wave = tid >> 6;     // 0..15
    const int lane = tid & 63;

    __shared__ __align__(16) float4 A1l[LL * A1STRIDE];   // 133 KB a1 cache
    __shared__ __align__(16) float4 part4[1024];          // 16 KB
    __shared__ __align__(16) float4 wws4[DD / 4];
    __shared__ float s1[LL], s2[LL], E1[LL], E2m[LL];
    __shared__ float cntR[LL], cntC[LL];
    __shared__ float rsv[LL], csv[LL];
    __shared__ float redS[16], redM[16];
    __shared__ __align__(16) float4 ps4[DD / 4];

    const int l1 = len1[b];
    const int l2 = len2[b];

    if (tid < DD / 4) wws4[tid] = ((const float4*)ww)[tid];
    __syncthreads();

    const float* __restrict__ A1 = a1 + (size_t)b * LL * DD;
    const float* __restrict__ A2 = a2 + (size_t)b * LL * DD;

    // ---- phase 1: 256 row-dots, 4 threads per row; a1 rows cached in LDS ----
    {
        const int r = tid >> 2;            // 0..255 (first half a1, second a2)
        const int t = tid & 3;
        float ax = 0.f, ay = 0.f, az = 0.f, aw = 0.f;
        if (r < LL) {
            const float4* __restrict__ row = (const float4*)(A1 + (size_t)r * DD);
#pragma unroll
            for (int qq = 0; qq < 16; ++qq) {
                const int idx = qq * 4 + t;
                const float4 v = row[idx];
                A1l[r * A1STRIDE + idx] = v;
                const float4 w = wws4[idx];
                ax += v.x * w.x; ay += v.y * w.y; az += v.z * w.z; aw += v.w * w.w;
            }
        } else {
            const float4* __restrict__ row = (const float4*)(A2 + (size_t)(r - LL) * DD);
#pragma unroll
            for (int qq = 0; qq < 16; ++qq) {
                const int idx = qq * 4 + t;
                const float4 v = row[idx];
                const float4 w = wws4[idx];
                ax += v.x * w.x; ay += v.y * w.y; az += v.z * w.z; aw += v.w * w.w;
            }
        }
        float s = (ax + ay) + (az + aw);
        s += __shfl_xor(s, 1, 64);
        s += __shfl_xor(s, 2, 64);
        if (t == 0) { if (r < LL) s1[r] = s; else s2[r - LL] = s; }
    }
    __syncthreads();

    // ---- phase 2: E1=e^{s1}, E2m=e^{-s2}; S1,S2 over valid entries ----
    {
        float v = 0.f;
        if (tid < LL) {
            const float e = expf(s1[tid]);
            E1[tid] = e;
            if (tid < l1) v = e;
        } else if (tid < 2 * LL) {
            const int j = tid - LL;
            const float e = expf(-s2[j]);
            E2m[j] = e;
            if (j < l2) v = e;
        }
        v = waveReduceSum(v);
        if (lane == 0) redS[wave] = v;     // waves 0,1 -> S1; waves 2,3 -> S2
    }
    __syncthreads();

    // ---- phase 3a: per-row / per-col masked counts, runtime-bounded loops ----
    {
        const int rr  = tid >> 2;          // 0..255
        const int sub = tid & 3;
        int c = 0;
        if (rr < LL) {
            if (rr < l1) {
                const float si = s1[rr];
                for (int j = sub; j < l2; j += 4)
                    if (fabsf(si - s2[j]) < 1e-7f) c++;
            }
        } else {
            const int jj = rr - LL;
            if (jj < l2) {
                const float sj = s2[jj];
                for (int i = sub; i < l1; i += 4)
                    if (fabsf(s1[i] - sj) < 1e-7f) c++;
            }
        }
        c += __shfl_xor(c, 1, 64);
        c += __shfl_xor(c, 2, 64);
        if (sub == 0) {
            if (rr < LL) cntR[rr] = (float)c;       // raw row count
            else         cntC[rr - LL] = (float)c;  // raw col count
        }
    }
    __syncthreads();

    // ---- phase 3b: Mtot = sum of row counts over valid rows -> dinv ----
    {
        float mc = (tid < LL && tid < l1) ? cntR[tid] : 0.f;
        mc = waveReduceSum(mc);
        if (lane == 0) redM[wave] = mc;
    }
    __syncthreads();
    const float S1 = redS[0] + redS[1];
    const float S2 = redS[2] + redS[3];
    const float Mtot = redM[0] + redM[1];      // only waves 0,1 have tid<LL
    const float dinv = 1.0f / (S1 * S2 - Mtot);

    // ---- phase 3c: finalize rsv/csv (pre-scaled by dinv) ----
    if (tid < LL)
        rsv[tid] = (tid < l1) ? (E1[tid] * S2 - cntR[tid]) * dinv : 0.f;
    else if (tid < 2 * LL) {
        const int j = tid - LL;
        csv[j] = (j < l2) ? (E2m[j] * S1 - cntC[j]) * dinv : 0.f;
    }
    __syncthreads();

    // ---- phase 4: pooled, float4-vectorized: wave g owns rows 8g..8g+7 ----
    {
        const int d4 = tid & 63;           // float4 column 0..63
        const int g  = tid >> 6;           // 0..15
        const float4* __restrict__ A2v = (const float4*)A2;
        float4 acc = make_float4(0.f, 0.f, 0.f, 0.f);
#pragma unroll
        for (int k = 0; k < 8; ++k) {
            const int i = g * 8 + k;
            const float4 va = A1l[i * A1STRIDE + d4];
            const float4 vb = A2v[i * 64 + d4];
            const float r_ = rsv[i], c_ = csv[i];
            acc.x += r_ * va.x - c_ * vb.x;
            acc.y += r_ * va.y - c_ * vb.y;
            acc.z += r_ * va.z - c_ * vb.z;
            acc.w += r_ * va.w - c_ * vb.w;
        }
        part4[tid] = acc;
    }
    __syncthreads();
    // two-step partial reduction: 256 threads x 4, then 64 x 4
    if (tid < 256) {
        float4 p = part4[tid];
        const float4 p1 = part4[256 + tid];
        const float4 p2 = part4[512 + tid];
        const float4 p3 = part4[768 + tid];
        p.x += p1.x + p2.x + p3.x;
        p.y += p1.y + p2.y + p3.y;
        p.z += p1.z + p2.z + p3.z;
        p.w += p1.w + p2.w + p3.w;
        part4[tid] = p;
    }
    __syncthreads();
    if (tid < 64) {
        float4 p = part4[tid];
        const float4 p1 = part4[64 + tid];
        const float4 p2 = part4[128 + tid];
        const float4 p3 = part4[192 + tid];
        p.x += p1.x + p2.x + p3.x;
        p.y += p1.y + p2.y + p3.y;
        p.z += p1.z + p2.z + p3.z;
        p.w += p1.w + p2.w + p3.w;
        ps4[tid] = p;
    }
    __syncthreads();

    // ---- phase 5: FC + tanh for eighth q8: 128 h rows, 64 rows/pass, 2 passes ----
    {
        const int hl  = tid >> 4;          // 0..63
        const int t16 = tid & 15;
        const float4 u0 = ps4[t16];
        const float4 u1 = ps4[16 + t16];
        const float4 u2 = ps4[32 + t16];
        const float4 u3 = ps4[48 + t16];
        float* __restrict__ outb = out + (size_t)b * HH;
#pragma unroll
        for (int pass = 0; pass < 2; ++pass) {
            const int h = q8 * 128 + pass * 64 + hl;
            const float4* __restrict__ wrow = (const float4*)(fcw + (size_t)h * DD);
            const float4 v0 = wrow[t16];
            const float4 v1 = wrow[16 + t16];
            const float4 v2 = wrow[32 + t16];
            const float4 v3 = wrow[48 + t16];
            float acc = v0.x * u0.x + v0.y * u0.y + v0.z * u0.z + v0.w * u0.w;
            acc      += v1.x * u1.x + v1.y * u1.y + v1.z * u1.z + v1.w * u1.w;
            acc      += v2.x * u2.x + v2.y * u2.y + v2.z * u2.z + v2.w * u2.w;
            acc      += v3.x * u3.x + v3.y * u3.y + v3.z * u3.z + v3.w * u3.w;
            acc += __shfl_xor(acc, 1, 64);
            acc += __shfl_xor(acc, 2, 64);
            acc += __shfl_xor(acc, 4, 64);
            acc += __shfl_xor(acc, 8, 64);
            if (t16 == 0) outb[h] = tanhf(acc + fcb[h]);
        }
    }
}

extern "C" void kernel_launch(void* const* d_in, const int* in_sizes, int n_in,
                              void* d_out, int out_size, void* d_ws, size_t ws_size,
                              hipStream_t stream) {
    const float* a1   = (const float*)d_in[0];
    const int*   len1 = (const int*)d_in[1];
    const float* a2   = (const float*)d_in[2];
    const int*   len2 = (const int*)d_in[3];
    const float* fcw  = (const float*)d_in[4];
    const float* fcb  = (const float*)d_in[5];
    const float* ww   = (const float*)d_in[6];
    float* out = (float*)d_out;

    batch_oct_kernel<<<256, 1024, 0, stream>>>(a1, len1, a2, len2, fcw, fcb, ww, out);
}